// Round 6
// baseline (48.320 us; speedup 1.0000x reference)
//
#include <hip/hip_runtime.h>

// VectorQuantizer, fully fused: fp16-MFMA filter + exact fp32 rescore in ONE
// kernel (plus one tiny cb-prep kernel).
// z_e [16,1024,256] f32, codebook [1024,256] f32
// out = concat( z_q [16,1024,256] f32 , indices [16,1024] as f32 )
//
// vq_prep_cb: cb -> fp16 MFMA-fragment order + exact fp32 csq
// vq_fused  : per block (64 rows, 512 thr = 8 waves):
//   P1 stage z -> fp16 fragments in LDS (reads z f32 in 128B/row segments)
//   P2 wave wv scores codes [wv*128, wv*128+128) via 16x16x32 f16 MFMA;
//      u32 keys (truncated score | idx), DPP row top-2, red[8][64] in LDS
//   P3 wave-per-8-rows: merge wave-pair top-2 -> 8 cands/row, exact fp32
//      rescore (DPP add-reduce), argmin, gather z_q, write idx.

#define M_ROWS 16384
#define DDIM   256
#define NCODES 1024

typedef _Float16 half8 __attribute__((ext_vector_type(8)));
typedef float    f32x4 __attribute__((ext_vector_type(4)));

__device__ __forceinline__ unsigned int f2ord(float f) {
    unsigned int u = __float_as_uint(f);
    return (u & 0x80000000u) ? ~u : (u | 0x80000000u);
}

#define DPP_SELF(k, ctrl) \
    ((unsigned)__builtin_amdgcn_update_dpp((int)(k), (int)(k), (ctrl), 0xF, 0xF, false))
#define DPP_Z(v, ctrl) \
    __builtin_amdgcn_update_dpp(0, (v), (ctrl), 0xF, 0xF, true)

// 64-lane sum via DPP; total valid in lane 63
__device__ __forceinline__ float dpp_radd(float x) {
    float s = x;
    s += __int_as_float(DPP_Z(__float_as_int(s), 0x111));  // row_shr:1
    s += __int_as_float(DPP_Z(__float_as_int(s), 0x112));  // row_shr:2
    s += __int_as_float(DPP_Z(__float_as_int(s), 0x114));  // row_shr:4
    s += __int_as_float(DPP_Z(__float_as_int(s), 0x118));  // row_shr:8
    s += __int_as_float(DPP_Z(__float_as_int(s), 0x142));  // row_bcast:15
    s += __int_as_float(DPP_Z(__float_as_int(s), 0x143));  // row_bcast:31
    return s;
}

// ---------------- prep cb: pack (blocks 0..127) + csq (blocks 128..383) ----
__global__ __launch_bounds__(256) void vq_prep_cb(const float* __restrict__ cb,
                                                  _Float16* __restrict__ chp,
                                                  float* __restrict__ csq) {
    if (blockIdx.x < 128) {
        const int gid = blockIdx.x * 256 + threadIdx.x;
        const int l   = gid & 63;
        const int g   = gid >> 6;
        const int kt  = g & 7;
        const int rt  = g >> 3;
        const int row = rt * 16 + (l & 15);
        const int k0  = kt * 32 + (l >> 4) * 8;
        const float4 v0 = *reinterpret_cast<const float4*>(cb + (size_t)row * DDIM + k0);
        const float4 v1 = *reinterpret_cast<const float4*>(cb + (size_t)row * DDIM + k0 + 4);
        half8 h;
        h[0] = (_Float16)v0.x; h[1] = (_Float16)v0.y; h[2] = (_Float16)v0.z; h[3] = (_Float16)v0.w;
        h[4] = (_Float16)v1.x; h[5] = (_Float16)v1.y; h[6] = (_Float16)v1.z; h[7] = (_Float16)v1.w;
        *reinterpret_cast<half8*>(chp + (size_t)gid * 8) = h;
    } else {
        const int code = (blockIdx.x - 128) * 4 + (threadIdx.x >> 6);
        const int lane = threadIdx.x & 63;
        const float4 v = *reinterpret_cast<const float4*>(cb + (size_t)code * DDIM + lane * 4);
        float s = v.x * v.x + v.y * v.y + v.z * v.z + v.w * v.w;
        s = dpp_radd(s);
        if (lane == 63) csq[code] = s;
    }
}

// ---------------- fused: score + select + rescore + gather ----------------
__global__ __launch_bounds__(512) void vq_fused(const float* __restrict__ z,
                                                const _Float16* __restrict__ Bp,
                                                const float* __restrict__ cb,
                                                const float* __restrict__ csq,
                                                float* __restrict__ zq,
                                                float* __restrict__ outIdx) {
    __shared__ __align__(16) _Float16 Ah[64 * 256];   // 32 KB fragment-order
    __shared__ uint2 red[8][64];                      // 4 KB top-2 per wave/row

    const int tid  = threadIdx.x;
    const int lane = tid & 63;
    const int wv   = tid >> 6;            // 0..7
    const int rowBase = blockIdx.x * 64;

    // ---- P1: stage A tile as fp16 fragments ----
#pragma unroll
    for (int i = 0; i < 4; ++i) {
        const int g  = i * 8 + wv;        // 0..31 = m*8 + kt
        const int m  = g >> 3;
        const int kt = g & 7;
        const int row = rowBase + m * 16 + (lane & 15);
        const int k0  = kt * 32 + (lane >> 4) * 8;
        const float4 v0 = *reinterpret_cast<const float4*>(z + (size_t)row * DDIM + k0);
        const float4 v1 = *reinterpret_cast<const float4*>(z + (size_t)row * DDIM + k0 + 4);
        half8 h;
        h[0] = (_Float16)v0.x; h[1] = (_Float16)v0.y; h[2] = (_Float16)v0.z; h[3] = (_Float16)v0.w;
        h[4] = (_Float16)v1.x; h[5] = (_Float16)v1.y; h[6] = (_Float16)v1.z; h[7] = (_Float16)v1.w;
        *reinterpret_cast<half8*>(&Ah[g * 512 + lane * 8]) = h;
    }
    __syncthreads();

    // ---- P2: MFMA scores for this wave's 128 codes, u32-key top-2 ----
    const half8* __restrict__ B = reinterpret_cast<const half8*>(Bp);
    const int cx = lane & 15;
    const int q  = lane >> 4;

    unsigned kA[4][4], kB[4][4];
#pragma unroll
    for (int m = 0; m < 4; ++m)
#pragma unroll
        for (int r = 0; r < 4; ++r) { kA[m][r] = 0xFFFFFFFFu; kB[m][r] = 0xFFFFFFFFu; }

#pragma unroll
    for (int ct = 0; ct < 2; ++ct) {
        const int colTile = wv * 2 + ct;      // 0..15
        const int colBase = colTile * 64;

        f32x4 acc[4][4];
#pragma unroll
        for (int m = 0; m < 4; ++m)
#pragma unroll
            for (int n = 0; n < 4; ++n) acc[m][n] = (f32x4){0.f, 0.f, 0.f, 0.f};

#pragma unroll
        for (int kt = 0; kt < 8; ++kt) {
            half8 a[4], b[4];
#pragma unroll
            for (int m = 0; m < 4; ++m)
                a[m] = *reinterpret_cast<const half8*>(&Ah[(m * 8 + kt) * 512 + lane * 8]);
#pragma unroll
            for (int n = 0; n < 4; ++n)
                b[n] = B[(size_t)(((colTile * 4 + n) * 8 + kt) * 64 + lane)];
#pragma unroll
            for (int m = 0; m < 4; ++m)
#pragma unroll
                for (int n = 0; n < 4; ++n)
                    acc[m][n] = __builtin_amdgcn_mfma_f32_16x16x32_f16(a[m], b[n], acc[m][n], 0, 0, 0);
        }

        float csv[4];
#pragma unroll
        for (int n = 0; n < 4; ++n) csv[n] = csq[colBase + n * 16 + cx];

#pragma unroll
        for (int m = 0; m < 4; ++m)
#pragma unroll
            for (int r = 0; r < 4; ++r)
#pragma unroll
                for (int n = 0; n < 4; ++n) {
                    const float s = fmaf(-2.0f, acc[m][n][r], csv[n]);
                    const unsigned key = (f2ord(s) & 0xFFFFFC00u)
                                       | (unsigned)(colBase + n * 16 + cx);
                    if (key < kA[m][r]) { kB[m][r] = kA[m][r]; kA[m][r] = key; }
                    else if (key < kB[m][r]) { kB[m][r] = key; }
                }
    }

    // DPP top-2 merge across the 16 lanes of each DPP row
#pragma unroll
    for (int m = 0; m < 4; ++m)
#pragma unroll
        for (int r = 0; r < 4; ++r) {
            unsigned k0 = kA[m][r], k1 = kB[m][r];
#define MERGE_STEP(CTRL)                                              \
            {                                                         \
                const unsigned o0 = DPP_SELF(k0, CTRL);               \
                const unsigned o1 = DPP_SELF(k1, CTRL);               \
                const unsigned lo = (k0 < o0) ? k0 : o0;              \
                const unsigned hi = (k0 < o0) ? o0 : k0;              \
                const unsigned m1 = (k1 < o1) ? k1 : o1;              \
                k1 = (hi < m1) ? hi : m1;                             \
                k0 = lo;                                              \
            }
            MERGE_STEP(0x111)
            MERGE_STEP(0x112)
            MERGE_STEP(0x114)
            MERGE_STEP(0x118)
#undef MERGE_STEP
            if (cx == 15) red[wv][m * 16 + q * 4 + r] = make_uint2(k0, k1);
        }
    __syncthreads();

    // ---- P3: exact fp32 rescore of 8 cands/row + gather (8 rows/wave) ----
#pragma unroll
    for (int i = 0; i < 8; ++i) {
        const int rl  = wv * 8 + i;
        const int row = rowBase + rl;
        const float4 zv = *reinterpret_cast<const float4*>(z + (size_t)row * DDIM + lane * 4);

        unsigned cands[8];
#pragma unroll
        for (int g = 0; g < 4; ++g) {
            const uint2 x = red[2 * g][rl];
            const uint2 y = red[2 * g + 1][rl];
            const unsigned lo = (x.x < y.x) ? x.x : y.x;
            const unsigned hi = (x.x < y.x) ? y.x : x.x;
            const unsigned mn = (x.y < y.y) ? x.y : y.y;
            cands[2 * g]     = lo;
            cands[2 * g + 1] = (hi < mn) ? hi : mn;
        }

        float bestS = 3.4e38f;
        int   bestI = 0x7FFFFFFF;
#pragma unroll
        for (int c = 0; c < 8; ++c) {
            const int idx = (int)(cands[c] & 1023u);
            const float4 cv = *reinterpret_cast<const float4*>(cb + (size_t)idx * DDIM + lane * 4);
            float p = fmaf(zv.x, cv.x, fmaf(zv.y, cv.y, fmaf(zv.z, cv.z, zv.w * cv.w)));
            p = dpp_radd(p);
            p = __shfl(p, 63, 64);
            const float s = fmaf(-2.0f, p, csq[idx]);
            if (s < bestS || (s == bestS && idx < bestI)) { bestS = s; bestI = idx; }
        }

        if (lane == 0) outIdx[row] = (float)bestI;
        const float4 q4 = *reinterpret_cast<const float4*>(cb + (size_t)bestI * DDIM + lane * 4);
        *reinterpret_cast<float4*>(zq + (size_t)row * DDIM + lane * 4) = q4;
    }
}

extern "C" void kernel_launch(void* const* d_in, const int* in_sizes, int n_in,
                              void* d_out, int out_size, void* d_ws, size_t ws_size,
                              hipStream_t stream) {
    const float* z  = (const float*)d_in[0];   // [16384,256]
    const float* cb = (const float*)d_in[1];   // [1024,256]
    float* out    = (float*)d_out;
    float* zq     = out;                            // 16.77 MB
    float* outIdx = out + (size_t)M_ROWS * DDIM;    // 64 KB

    char* ws = (char*)d_ws;
    _Float16* chp = (_Float16*)ws;                  // 512 KB
    float* csq    = (float*)(ws + 512 * 1024);      // 4 KB

    vq_prep_cb<<<384, 256, 0, stream>>>(cb, chp, csq);
    vq_fused<<<M_ROWS / 64, 512, 0, stream>>>(z, chp, cb, csq, zq, outIdx);
}